// Round 6
// baseline (1247.294 us; speedup 1.0000x reference)
//
#include <hip/hip_runtime.h>
#include <math.h>

// ---------------------------------------------------------------------------
// ModularSelectCascadeNet forward. B=16384, M=8, NUM_LAYERS=4.
// R6: h_big eliminated. Fused mod-einsum megakernel (stats pass + full pass:
//     MFMA -> bn2 -> cascade -> last GEMM in one kernel). Wt2 in MFMA-fragment
//     layout streamed from L2 to VGPRs; A staged via swizzled global_load_lds.
// ---------------------------------------------------------------------------

#define EPI_NONE  0
#define EPI_RELU  1
#define EPI_TANH  2
#define EPI_COND  3
#define EPI_STATS 4

typedef short bf16x8 __attribute__((ext_vector_type(8)));
typedef float f32x4 __attribute__((ext_vector_type(4)));

__device__ __forceinline__ unsigned short f2bf(float f) {
  unsigned u = __float_as_uint(f);
  u += 0x7fffu + ((u >> 16) & 1u);
  return (unsigned short)(u >> 16);
}
__device__ __forceinline__ float bf2f(unsigned short h) {
  return __uint_as_float(((unsigned)h) << 16);
}
__device__ __forceinline__ void gload_lds16(const void* g, void* l) {
  __builtin_amdgcn_global_load_lds(
      (const __attribute__((address_space(1))) unsigned int*)g,
      (__attribute__((address_space(3))) unsigned int*)l, 16, 0, 0);
}
__device__ __forceinline__ bf16x8 relu_bf8(bf16x8 v) {
  bf16x8 r;
  #pragma unroll
  for (int j = 0; j < 8; ++j) r[j] = v[j] > 0 ? v[j] : (short)0;
  return r;
}

// ---------------------------------------------------------------------------
// Fused prep: converts x/emb to bf16, transposes all weights to bf16 [N][K]
// (zero-padded), lastW -> bf16 [64][256] (rows 18..63 zero), zeroes stats.
__global__ __launch_bounds__(256) void prep_all(
    const float* __restrict__ x, const float* __restrict__ embi,
    const float* __restrict__ base_W0, const float* __restrict__ em_W0,
    const float* __restrict__ base_W1, const float* __restrict__ gat_W0,
    const float* __restrict__ gat_W1, const float* __restrict__ sel_W,
    const float* __restrict__ cond_W, const float* __restrict__ last_W,
    unsigned short* __restrict__ x_bf, unsigned short* __restrict__ e_bf,
    unsigned short* __restrict__ W0t, unsigned short* __restrict__ emW0t,
    unsigned short* __restrict__ W1t, unsigned short* __restrict__ g0t,
    unsigned short* __restrict__ g1t, unsigned short* __restrict__ selWt,
    unsigned short* __restrict__ condWt, unsigned short* __restrict__ lastWt,
    float* __restrict__ stats)
{
  __shared__ float t[32][33];
  int bid = blockIdx.x;
  const int tid = threadIdx.x;

  if (bid < 4096) {  // fp32 -> bf16 converts
    const float* src = bid < 2048 ? x : embi;
    unsigned short* dst = bid < 2048 ? x_bf : e_bf;
    const int i = ((bid & 2047) * 256 + tid) * 4;
    const float4 v = *reinterpret_cast<const float4*>(&src[i]);
    ushort4 o;
    o.x = f2bf(v.x); o.y = f2bf(v.y); o.z = f2bf(v.z); o.w = f2bf(v.w);
    *reinterpret_cast<ushort4*>(&dst[i]) = o;
    return;
  }
  bid -= 4096;

  const int tx = tid & 31, ty = tid >> 5;

  if (bid < 496) {  // bf16 weight transposes: W[K][N] -> Wt[NP][KP]
    const float* src; unsigned short* dst; int K, N, KP, gx, local;
    if (bid < 64)       { src = base_W0; dst = W0t;   K = 128; N = 400; KP = 128; gx = 4;  local = bid; }
    else if (bid < 128) { src = em_W0;   dst = emW0t; K = 128; N = 400; KP = 128; gx = 4;  local = bid - 64; }
    else if (bid < 232) { src = base_W1; dst = W1t;   K = 400; N = 256; KP = 416; gx = 13; local = bid - 128; }
    else if (bid < 336) { src = gat_W0;  dst = g0t;   K = 400; N = 256; KP = 416; gx = 13; local = bid - 232; }
    else if (bid < 400) { src = gat_W1;  dst = g1t;   K = 256; N = 256; KP = 256; gx = 8;  local = bid - 336; }
    else if (bid < 448) {
      const int i = (bid - 400) / 16;
      src = sel_W + i * 16384; dst = selWt + i * 16384;
      K = 256; N = 64; KP = 256; gx = 8; local = (bid - 400) % 16;
    } else {
      const int i = (bid - 448) / 16;
      src = cond_W + i * 16384; dst = condWt + i * 16384;
      K = 64; N = 256; KP = 64; gx = 2; local = (bid - 448) % 16;
    }
    const int k0 = (local % gx) * 32, n0 = (local / gx) * 32;
    #pragma unroll
    for (int p = 0; p < 4; ++p) {
      const int k = k0 + ty + p * 8;
      t[ty + p * 8][tx] = (k < K && n0 + tx < N) ? src[(size_t)k * N + n0 + tx] : 0.f;
    }
    __syncthreads();
    #pragma unroll
    for (int p = 0; p < 4; ++p) {
      const int n = n0 + ty + p * 8;
      dst[(size_t)n * KP + k0 + tx] = f2bf(t[tx][ty + p * 8]);
    }
    return;
  }
  bid -= 496;

  if (bid < 8) {  // lastW: [256][18] -> bf16 [64][256], rows 18..63 zero
    const int k0 = bid * 32;
    #pragma unroll
    for (int p = 0; p < 4; ++p)
      t[ty + p * 8][tx] = (tx < 18) ? last_W[(size_t)(k0 + ty + p * 8) * 18 + tx] : 0.f;
    __syncthreads();
    #pragma unroll
    for (int p = 0; p < 4; ++p) {
      const int n = ty + p * 8;
      lastWt[(size_t)n * 256 + k0 + tx] = f2bf(t[tx][n]);
      lastWt[(size_t)(n + 32) * 256 + k0 + tx] = 0;
    }
    return;
  }

  for (int i = tid; i < 4608; i += 256) stats[i] = 0.f;
}

// ---------------------------------------------------------------------------
// Generic bf16 MFMA GEMM for the front chain. BM=128, BK=32.
template<int BN, int WM, int WN, int EPI, bool RELU_A>
__global__ __launch_bounds__(256) void gemm_bf16(
    const unsigned short* __restrict__ A, int AS,
    const unsigned short* __restrict__ Wt, const float* __restrict__ bias,
    unsigned short* __restrict__ C, int CS, int Nreal, int NP, int K,
    const unsigned short* __restrict__ emb,
    float* __restrict__ sum, float* __restrict__ sumsq)
{
  constexpr int FRAG_M = 128 / WM / 16;
  constexpr int FRAG_N = BN / WN / 16;
  __shared__ unsigned short As[128 * 32];
  __shared__ unsigned short Bs[BN * 32];
  const int row0 = blockIdx.y * 128;
  const int n0 = blockIdx.x * BN;
  const int tid = threadIdx.x;
  const int wid = tid >> 6, lane = tid & 63;
  const int wr = wid / WN, wc = wid % WN;
  const int arow = tid >> 2;
  const int kcol = (tid & 3) * 8;
  const int lr = lane & 15, lk = (lane >> 4) * 8;
  const int lrow = (lane >> 4) * 4;

  f32x4 acc[FRAG_M][FRAG_N] = {};
  for (int k0 = 0; k0 < K; k0 += 32) {
    gload_lds16(A + (size_t)(row0 + arow) * AS + k0 + kcol, (char*)As + tid * 16);
    gload_lds16(A + (size_t)(row0 + 64 + arow) * AS + k0 + kcol, (char*)As + 4096 + tid * 16);
    gload_lds16(Wt + (size_t)(n0 + arow) * K + k0 + kcol, (char*)Bs + tid * 16);
    if constexpr (BN == 128)
      gload_lds16(Wt + (size_t)(n0 + 64 + arow) * K + k0 + kcol, (char*)Bs + 4096 + tid * 16);
    __syncthreads();
    bf16x8 a[FRAG_M], b[FRAG_N];
    #pragma unroll
    for (int i = 0; i < FRAG_M; ++i) {
      a[i] = *reinterpret_cast<const bf16x8*>(&As[(wr * (128 / WM) + i * 16 + lr) * 32 + lk]);
      if (RELU_A) a[i] = relu_bf8(a[i]);
    }
    #pragma unroll
    for (int j = 0; j < FRAG_N; ++j)
      b[j] = *reinterpret_cast<const bf16x8*>(&Bs[(wc * (BN / WN) + j * 16 + lr) * 32 + lk]);
    #pragma unroll
    for (int i = 0; i < FRAG_M; ++i)
      #pragma unroll
      for (int j = 0; j < FRAG_N; ++j)
        acc[i][j] = __builtin_amdgcn_mfma_f32_16x16x32_bf16(a[i], b[j], acc[i][j], 0, 0, 0);
    __syncthreads();
  }
  #pragma unroll
  for (int j = 0; j < FRAG_N; ++j) {
    const int col = n0 + wc * (BN / WN) + j * 16 + lr;
    if (col >= NP) continue;
    const bool real = col < Nreal;
    const float bv = real ? bias[col] : 0.f;
    float s = 0.f, q = 0.f;
    #pragma unroll
    for (int i = 0; i < FRAG_M; ++i) {
      #pragma unroll
      for (int r = 0; r < 4; ++r) {
        const int row = row0 + wr * (128 / WM) + i * 16 + lrow + r;
        float v = acc[i][j][r] + bv;
        if (EPI == EPI_RELU) v = fmaxf(v, 0.f);
        if (EPI == EPI_TANH) v = tanhf(v);
        if (EPI == EPI_COND) { v *= bf2f(emb[(size_t)row * 256 + col]); v = fmaxf(v, 0.f); }
        if (!real) v = 0.f;
        const unsigned short hv = f2bf(v);
        C[(size_t)row * CS + col] = hv;
        if (EPI == EPI_STATS) {
          const float vr = bf2f(hv);
          s += vr;
          q = fmaf(vr, vr, q);
        }
      }
    }
    if (EPI == EPI_STATS) {
      s += __shfl_xor(s, 16); s += __shfl_xor(s, 32);
      q += __shfl_xor(q, 16); q += __shfl_xor(q, 32);
      if (lane < 16) {
        atomicAdd(&sum[col], s);
        atomicAdd(&sumsq[col], q);
      }
    }
  }
}

// ---------------------------------------------------------------------------
// Gumbel softmax over groups of 8 (bf16 logits).
__global__ void gumbel8(const unsigned short* __restrict__ logit, const float* __restrict__ u,
                        float* __restrict__ out, int u_off, int u_stride)
{
  const int idx = blockIdx.x * 256 + threadIdx.x;
  const int b = idx >> 3, m = idx & 7;
  const unsigned short* lp = logit + (size_t)b * 64 + m * 8;
  const float* up = u + (size_t)b * u_stride + u_off + m * 8;
  float v[8];
  #pragma unroll
  for (int j = 0; j < 8; ++j) {
    const float uu = fminf(fmaxf(up[j], 1e-10f), 0.9999999f);
    v[j] = bf2f(lp[j]) - logf(-logf(uu));
  }
  float mx = v[0];
  #pragma unroll
  for (int j = 1; j < 8; ++j) mx = fmaxf(mx, v[j]);
  float s = 0.f;
  #pragma unroll
  for (int j = 0; j < 8; ++j) { v[j] = expf(v[j] - mx); s += v[j]; }
  const float inv = 1.f / s;
  float* op = out + (size_t)b * 64 + m * 8;
  #pragma unroll
  for (int j = 0; j < 8; ++j) op[j] = v[j] * inv;
}

__global__ void final_select_k(const unsigned short* __restrict__ si, const float* __restrict__ Wf,
                               const float* __restrict__ bias, const float* __restrict__ u,
                               float* __restrict__ fs)
{
  const int idx = blockIdx.x * 256 + threadIdx.x;
  const int b = idx >> 3, j = idx & 7;
  const unsigned short* sp = si + (size_t)b * 256;
  float acc = bias[j];
  for (int k = 0; k < 256; ++k) acc = fmaf(bf2f(sp[k]), Wf[k * 8 + j], acc);
  const float uu = fminf(fmaxf(u[(size_t)b * 8 + j], 1e-10f), 0.9999999f);
  float v = acc - logf(-logf(uu));
  float mx = v;
  #pragma unroll
  for (int d = 1; d < 8; d <<= 1) mx = fmaxf(mx, __shfl_xor(mx, d, 8));
  float e = expf(v - mx);
  float s = e;
  #pragma unroll
  for (int d = 1; d < 8; d <<= 1) s += __shfl_xor(s, d, 8);
  fs[(size_t)b * 8 + j] = e / s;
}

// ---------------------------------------------------------------------------
// Fold mod weights with inline bn1 finalize. grid (8, 8, 9).
__global__ __launch_bounds__(256) void fold_modw_all(
    const float* __restrict__ W, const float* __restrict__ g1,
    const float* __restrict__ b1, const float* __restrict__ modb,
    const float* __restrict__ sum1, const float* __restrict__ sumsq1,
    unsigned short* __restrict__ Wt, float* __restrict__ bias2)
{
  const float invB = 1.f / 16384.f;
  if (blockIdx.z == 8) {
    if (blockIdx.y != 0) return;
    const int m = blockIdx.x, h = threadIdx.x;
    float acc = modb[m * 256 + h];
    for (int d = 0; d < 256; ++d) {
      const float mean = sum1[d] * invB;
      const float var = sumsq1[d] * invB - mean * mean;
      const float r = rsqrtf(var + 1e-5f);
      const float c = b1[m * 256 + d] - mean * r * g1[m * 256 + d];
      acc = fmaf(c, W[((size_t)m * 256 + d) * 256 + h], acc);
    }
    bias2[m * 256 + h] = acc;
    return;
  }
  __shared__ float t[32][33];
  const int m = blockIdx.z, d0 = blockIdx.y * 32, h0 = blockIdx.x * 32;
  const int tx = threadIdx.x & 31, ty = threadIdx.x >> 5;
  #pragma unroll
  for (int p = 0; p < 4; ++p) {
    const int d = d0 + ty + p * 8;
    const float mean = sum1[d] * invB;
    const float var = sumsq1[d] * invB - mean * mean;
    const float r = rsqrtf(var + 1e-5f);
    t[ty + p * 8][tx] = W[((size_t)m * 256 + d) * 256 + h0 + tx] * r * g1[m * 256 + d];
  }
  __syncthreads();
  #pragma unroll
  for (int p = 0; p < 4; ++p) {
    const int h = h0 + ty + p * 8;
    Wt[((size_t)m * 256 + h) * 256 + d0 + tx] = f2bf(t[tx][ty + p * 8]);
  }
}

// Reshuffle modWt [m][h][d] -> Wt2 MFMA-fragment layout:
// frag (m, j=h>>4, ks=d>>5) of 512 bf16: [hi=(d&31)>>3][lr=h&15][e=d&7].
// thread per (m, col, ks); 64 blocks x 256.
__global__ __launch_bounds__(256) void reshuffle_w(
    const unsigned short* __restrict__ modWt, unsigned short* __restrict__ Wt2)
{
  const int idx = blockIdx.x * 256 + threadIdx.x;   // 16384
  const int ks = idx & 7, col = (idx >> 3) & 255, m = idx >> 11;
  const unsigned short* src = modWt + ((size_t)m * 256 + col) * 256 + ks * 32;
  unsigned short* dst = Wt2 + (size_t)((m * 16 + (col >> 4)) * 8 + ks) * 512 + (col & 15) * 8;
  #pragma unroll
  for (int h2 = 0; h2 < 4; ++h2)
    *reinterpret_cast<uint4*>(dst + h2 * 128) = *reinterpret_cast<const uint4*>(src + h2 * 8);
}

// bn2 finalize with bias2 folded into shift: H_bn = Hraw*scale + shift.
__global__ void finalize_bn2(const float* __restrict__ sum, const float* __restrict__ sumsq,
                             const float* __restrict__ bias2, const float* __restrict__ g,
                             const float* __restrict__ b, float* __restrict__ scale,
                             float* __restrict__ shift)
{
  const int i = blockIdx.x * 256 + threadIdx.x;   // 2048
  const float invB = 1.f / 16384.f;
  const float m = sum[i] * invB;
  const float v = sumsq[i] * invB - m * m;
  const float sc = rsqrtf(v + 1e-5f) * g[i];
  scale[i] = sc;
  shift[i] = (bias2[i] - m) * sc + b[i];
}

// ---------------------------------------------------------------------------
// Megakernel: mod-einsum (32 samples/block, wave m owns 256 cols of module m).
// STATS pass: accumulate bn2 column stats of H+bias2 (no store).
// FULL pass: H -> bn2 apply -> 3 cascade rounds -> final mix -> last GEMM.
// 512 threads (8 waves), 512 blocks.
template<bool STATS>
__global__ __launch_bounds__(512, 2) void mega_mod(
    const unsigned short* __restrict__ Abf,   // out_bf [16384][256]
    const unsigned short* __restrict__ Wt2,   // fragment layout, 1 MB
    const float* __restrict__ bias2,
    float* __restrict__ sum, float* __restrict__ sumsq,
    const float* __restrict__ scale2, const float* __restrict__ shift2,
    const float* __restrict__ gs0, const float* __restrict__ gs1,
    const float* __restrict__ gs2, const float* __restrict__ fs,
    const unsigned short* __restrict__ lastWt, const float* __restrict__ lastb,
    float* __restrict__ out)
{
  __shared__ __align__(16) unsigned char LDSBUF[51456];
  unsigned short* A_lds = (unsigned short*)LDSBUF;             // 16 KB (K-loop)
  unsigned short* Hs    = (unsigned short*)LDSBUF;             // 34560 B (slices; A dead)
  unsigned short* ovl   = (unsigned short*)(LDSBUF + 34560);   // [32][264] bf16

  const int tid = threadIdx.x;
  const int wv = tid >> 6;           // wave == module m
  const int lane = tid & 63;
  const int lr = lane & 15, hi = lane >> 4;
  const int b0 = blockIdx.x * 32;

  // Stage A tile [32][256] bf16 with chunk^=(row&7) swizzle (pre-swz source).
  {
    const int row0 = tid >> 5;           // 0..15
    const int cg = (tid & 31) ^ (row0 & 7);
    gload_lds16(Abf + (size_t)(b0 + row0) * 256 + cg * 8, (char*)A_lds + tid * 16);
    gload_lds16(Abf + (size_t)(b0 + 16 + row0) * 256 + cg * 8,
                (char*)LDSBUF + 8192 + tid * 16);
  }
  __syncthreads();

  f32x4 acc[2][16] = {};
  for (int ks = 0; ks < 8; ++ks) {
    bf16x8 a[2];
    #pragma unroll
    for (int i = 0; i < 2; ++i) {
      const int row = i * 16 + lr;
      const int ch = (ks * 4 + hi) ^ (row & 7);
      a[i] = *reinterpret_cast<const bf16x8*>(&A_lds[row * 256 + ch * 8]);
    }
    #pragma unroll
    for (int j = 0; j < 16; ++j) {
      const bf16x8 b = *reinterpret_cast<const bf16x8*>(
          Wt2 + (size_t)((wv * 16 + j) * 8 + ks) * 512 + lane * 8);
      acc[0][j] = __builtin_amdgcn_mfma_f32_16x16x32_bf16(a[0], b, acc[0][j], 0, 0, 0);
      acc[1][j] = __builtin_amdgcn_mfma_f32_16x16x32_bf16(a[1], b, acc[1][j], 0, 0, 0);
    }
  }

  if (STATS) {
    #pragma unroll
    for (int j = 0; j < 16; ++j) {
      const int gc = wv * 256 + j * 16 + lr;
      const float bv = bias2[gc];
      float s = 0.f, q = 0.f;
      #pragma unroll
      for (int i = 0; i < 2; ++i)
        #pragma unroll
        for (int r = 0; r < 4; ++r) {
          const float v = acc[i][j][r] + bv;
          s += v;
          q = fmaf(v, v, q);
        }
      s += __shfl_xor(s, 16); s += __shfl_xor(s, 32);
      q += __shfl_xor(q, 16); q += __shfl_xor(q, 32);
      if (lane < 16) {
        atomicAdd(&sum[gc], s);
        atomicAdd(&sumsq[gc], q);
      }
    }
    return;
  }

  // FULL: cascade slice-by-slice (4 slices of 64 cols).
  for (int t = 0; t < 4; ++t) {
    __syncthreads();   // t=0: protect A reads; t>0: protect prior slice reads
    #pragma unroll
    for (int jj = 0; jj < 4; ++jj) {
      const int j = t * 4 + jj;
      #pragma unroll
      for (int i = 0; i < 2; ++i)
        #pragma unroll
        for (int r = 0; r < 4; ++r) {
          const int s = i * 16 + hi * 4 + r;
          Hs[s * 540 + wv * 66 + jj * 16 + lr] = f2bf(acc[i][j][r]);
        }
    }
    __syncthreads();
    const int col = lane;   // 0..63
    float sc_r[8], sh_r[8];
    #pragma unroll
    for (int m = 0; m < 8; ++m) {
      const int gc = m * 256 + t * 64 + col;
      sc_r[m] = scale2[gc];
      sh_r[m] = shift2[gc];
    }
    #pragma unroll
    for (int p = 0; p < 4; ++p) {
      const int s = wv * 4 + p;
      const int bg = b0 + s;
      float prev[8];
      #pragma unroll
      for (int m = 0; m < 8; ++m)
        prev[m] = bf2f(Hs[s * 540 + m * 66 + col]) * sc_r[m] + sh_r[m];
      const float* sel_l[3] = { gs2 + (size_t)bg * 64, gs1 + (size_t)bg * 64,
                                gs0 + (size_t)bg * 64 };
      #pragma unroll
      for (int l = 0; l < 3; ++l) {
        const float* sp = sel_l[l];
        float nw[8];
        #pragma unroll
        for (int mm = 0; mm < 8; ++mm) {
          float a = 0.f;
          #pragma unroll
          for (int k = 0; k < 8; ++k) a = fmaf(sp[mm * 8 + k], prev[k], a);
          nw[mm] = fmaxf(a, 0.f);
        }
        #pragma unroll
        for (int mm = 0; mm < 8; ++mm) prev[mm] = nw[mm];
      }
      const float* fp = fs + (size_t)bg * 8;
      float o = 0.f;
      #pragma unroll
      for (int m = 0; m < 8; ++m) o = fmaf(fp[m], prev[m], o);
      ovl[s * 264 + t * 64 + col] = f2bf(o);
    }
  }
  __syncthreads();

  // Fused last GEMM: waves 0,1; 16 samples each; cols 0..31 (18 real), K=256.
  if (wv < 2) {
    f32x4 acc2[2] = {};
    #pragma unroll
    for (int ks = 0; ks < 8; ++ks) {
      const bf16x8 a = *reinterpret_cast<const bf16x8*>(
          &ovl[(wv * 16 + lr) * 264 + ks * 32 + hi * 8]);
      #pragma unroll
      for (int j = 0; j < 2; ++j) {
        const bf16x8 b = *reinterpret_cast<const bf16x8*>(
            lastWt + (size_t)(j * 16 + lr) * 256 + ks * 32 + hi * 8);
        acc2[j] = __builtin_amdgcn_mfma_f32_16x16x32_bf16(a, b, acc2[j], 0, 0, 0);
      }
    }
    #pragma unroll
    for (int j = 0; j < 2; ++j) {
      const int colo = j * 16 + lr;
      if (colo < 18) {
        const float bv = lastb[colo];
        #pragma unroll
        for (int r = 0; r < 4; ++r) {
          const int srow = wv * 16 + hi * 4 + r;
          out[(size_t)(b0 + srow) * 18 + colo] = acc2[j][r] + bv;
        }
      }
    }
  }
}

extern "C" void kernel_launch(void* const* d_in, const int* in_sizes, int n_in,
                              void* d_out, int out_size, void* d_ws, size_t ws_size,
                              hipStream_t stream)
{
  (void)in_sizes; (void)n_in; (void)out_size; (void)ws_size;
  const float* x       = (const float*)d_in[0];
  const float* embi    = (const float*)d_in[1];
  const float* u_sel   = (const float*)d_in[2];
  const float* u_fin   = (const float*)d_in[3];
  const float* base_W0 = (const float*)d_in[4];
  const float* base_b0 = (const float*)d_in[5];
  const float* base_W1 = (const float*)d_in[6];
  const float* base_b1 = (const float*)d_in[7];
  const float* em_W0   = (const float*)d_in[8];
  const float* em_b0   = (const float*)d_in[9];
  const float* gat_W0  = (const float*)d_in[10];
  const float* gat_b0  = (const float*)d_in[11];
  const float* gat_W1  = (const float*)d_in[12];
  const float* gat_b1  = (const float*)d_in[13];
  const float* sel_W   = (const float*)d_in[14];
  const float* sel_b   = (const float*)d_in[15];
  const float* selF_W  = (const float*)d_in[16];
  const float* selF_b  = (const float*)d_in[17];
  const float* cond_W  = (const float*)d_in[18];
  const float* cond_b  = (const float*)d_in[19];
  const float* mod_W   = (const float*)d_in[20];
  const float* mod_b   = (const float*)d_in[21];
  const float* last_W  = (const float*)d_in[22];
  const float* last_b  = (const float*)d_in[23];
  const float* bn1_g   = (const float*)d_in[24];
  const float* bn1_b   = (const float*)d_in[25];
  const float* bn2_g   = (const float*)d_in[26];
  const float* bn2_b   = (const float*)d_in[27];

  // --- workspace layout (byte offsets) ---
  char* WSB = (char*)d_ws;
  unsigned short* Wt2      = (unsigned short*)(WSB + 0);          // 1 MB frag layout
  unsigned short* h1       = (unsigned short*)(WSB + 67108864);   // 16384x416
  unsigned short* x_bf     = (unsigned short*)(WSB + 80740352);   // 16384x128
  unsigned short* e_bf     = (unsigned short*)(WSB + 84934656);   // 16384x128
  unsigned short* emb_bf   = (unsigned short*)(WSB + 89128960);   // 16384x256
  unsigned short* si_bf    = (unsigned short*)(WSB + 97517568);   // 16384x256
  unsigned short* out_bf   = (unsigned short*)(WSB + 105906176);  // 16384x256
  unsigned short* logit_bf = (unsigned short*)(WSB + 114294784);  // 16384x64
  float* gs0   = (float*)(WSB + 116391936);  // 16384x64
  float* gs1   = (float*)(WSB + 120586240);
  float* gs2   = (float*)(WSB + 124780544);
  float* bufFs = (float*)(WSB + 128974848);  // 16384x8
  unsigned short* W0t   = (unsigned short*)(WSB + 129499136);  // 512x128
  unsigned short* emW0t = (unsigned short*)(WSB + 129630208);  // 512x128
  unsigned short* W1t   = (unsigned short*)(WSB + 129761280);  // 256x416
  unsigned short* g0t   = (unsigned short*)(WSB + 129974272);  // 256x416
  unsigned short* g1t   = (unsigned short*)(WSB + 130187264);  // 256x256
  unsigned short* selWt = (unsigned short*)(WSB + 130318336);  // 3x64x256
  unsigned short* condWt= (unsigned short*)(WSB + 130416640);  // 3x256x64
  unsigned short* modWt = (unsigned short*)(WSB + 130514944);  // 8x256x256
  float* bias2  = (float*)(WSB + 131563520);  // 2048
  float* stats  = (float*)(WSB + 131571712);  // 4608 floats
  unsigned short* lastWt = (unsigned short*)(WSB + 131590144); // 64x256 bf16
  float* scale2 = (float*)(WSB + 131622912);  // 2048
  float* shift2 = (float*)(WSB + 131631104);  // 2048
  float* sum1   = stats;        float* sumsq1 = stats + 256;
  float* sum2   = stats + 512;  float* sumsq2 = stats + 2560;

  const dim3 blk(256);
  // fused prep (converts + weight transposes + stats zero)
  prep_all<<<dim3(4601), blk, 0, stream>>>(
      x, embi, base_W0, em_W0, base_W1, gat_W0, gat_W1, sel_W, cond_W, last_W,
      x_bf, e_bf, W0t, emW0t, W1t, g0t, g1t, selWt, condWt, lastWt, stats);

  // base MLP: x -> relu -> out (fused bn1 stats)
  gemm_bf16<128, 2, 2, EPI_RELU, false><<<dim3(4, 128), blk, 0, stream>>>(
      x_bf, 128, W0t, base_b0, h1, 416, 400, 416, 128, nullptr, nullptr, nullptr);
  gemm_bf16<128, 2, 2, EPI_STATS, false><<<dim3(2, 128), blk, 0, stream>>>(
      h1, 416, W1t, base_b1, out_bf, 256, 256, 256, 416, nullptr, sum1, sumsq1);
  // embedding / gating
  gemm_bf16<128, 2, 2, EPI_RELU, false><<<dim3(4, 128), blk, 0, stream>>>(
      e_bf, 128, emW0t, em_b0, h1, 416, 400, 416, 128, nullptr, nullptr, nullptr);
  gemm_bf16<128, 2, 2, EPI_RELU, false><<<dim3(2, 128), blk, 0, stream>>>(
      h1, 416, g0t, gat_b0, si_bf, 256, 256, 256, 416, nullptr, nullptr, nullptr);
  gemm_bf16<128, 2, 2, EPI_NONE, false><<<dim3(2, 128), blk, 0, stream>>>(
      si_bf, 256, g1t, gat_b1, emb_bf, 256, 256, 256, 256, nullptr, nullptr, nullptr);
  // select loop
  float* gs[3] = {gs0, gs1, gs2};
  for (int i = 0; i < 3; ++i) {
    if (i == 0)
      gemm_bf16<64, 4, 1, EPI_TANH, true><<<dim3(1, 128), blk, 0, stream>>>(
          emb_bf, 256, selWt, sel_b, logit_bf, 64, 64, 64, 256, nullptr, nullptr, nullptr);
    else
      gemm_bf16<64, 4, 1, EPI_TANH, false><<<dim3(1, 128), blk, 0, stream>>>(
          si_bf, 256, selWt + i * 16384, sel_b + i * 64, logit_bf, 64, 64, 64, 256, nullptr, nullptr, nullptr);
    gumbel8<<<dim3(512), blk, 0, stream>>>(logit_bf, u_sel, gs[i], i * 64, 192);
    gemm_bf16<128, 2, 2, EPI_COND, false><<<dim3(2, 128), blk, 0, stream>>>(
        logit_bf, 64, condWt + i * 16384, cond_b + i * 256, si_bf, 256, 256, 256, 64, emb_bf, nullptr, nullptr);
  }
  final_select_k<<<dim3(512), blk, 0, stream>>>(si_bf, selF_W, selF_b, u_fin, bufFs);
  // bn1 finalize + mod weight fold + bias2 (one kernel), then fragment reshuffle
  fold_modw_all<<<dim3(8, 8, 9), blk, 0, stream>>>(
      mod_W, bn1_g, bn1_b, mod_b, sum1, sumsq1, modWt, bias2);
  reshuffle_w<<<dim3(64), blk, 0, stream>>>(modWt, Wt2);
  // pass A: bn2 stats (no H store)
  mega_mod<true><<<dim3(512), dim3(512), 0, stream>>>(
      out_bf, Wt2, bias2, sum2, sumsq2, nullptr, nullptr,
      nullptr, nullptr, nullptr, nullptr, nullptr, nullptr, nullptr);
  finalize_bn2<<<dim3(8), blk, 0, stream>>>(sum2, sumsq2, bias2, bn2_g, bn2_b, scale2, shift2);
  // pass B: fused einsum + bn2 + cascade + last GEMM
  mega_mod<false><<<dim3(512), dim3(512), 0, stream>>>(
      out_bf, Wt2, nullptr, nullptr, nullptr, scale2, shift2,
      gs0, gs1, gs2, bufFs, lastWt, last_b, (float*)d_out);
}